// Round 22
// baseline (4656.396 us; speedup 1.0000x reference)
//
#include <hip/hip_runtime.h>
#include <hip/hip_bf16.h>

#pragma clang fp contract(off)

#define NTH   1024      // 16 waves, 1 block per CU
#define PPT   16        // NTH*PPT == NPTS
#define NPTS  16384
#define BATCH 16
#define CFEAT 128
#define SMAX  4096
#define NWAVE (NTH / 64)
// Prune margin (r15-proven exact): skip iff lb*PRUNE_C >= waveMaxD(half).
#define PRUNE_C 0.999995f

typedef __attribute__((ext_vector_type(2))) float f32x2;

__device__ __forceinline__ unsigned spread3(unsigned v) {
    v &= 0x3FFu;
    v = (v | (v << 16)) & 0x030000FFu;
    v = (v | (v << 8))  & 0x0300F00Fu;
    v = (v | (v << 4))  & 0x030C30C3u;
    v = (v | (v << 2))  & 0x09249249u;
    return v;
}
__device__ __forceinline__ unsigned qz10(float v) {
    int q = (int)((v + 6.0f) * (1023.0f / 12.0f));   // layout-only
    q = q < 0 ? 0 : (q > 1023 ? 1023 : q);
    return (unsigned)q;
}
__device__ __forceinline__ unsigned morton30(float x, float y, float z) {
    return (spread3(qz10(x)) << 2) | (spread3(qz10(y)) << 1) | spread3(qz10(z));
}
// wave-uniform scalar hint (bbox constants -> SGPRs; VALU reads 1 SGPR/inst)
__device__ __forceinline__ float rfl_f(float v) {
    return __uint_as_float((unsigned)__builtin_amdgcn_readfirstlane(
        (int)__float_as_uint(v)));
}
// 64-lane max via DPP (r13-proven ctrl sequence), returns wave-uniform max
__device__ __forceinline__ unsigned wave_max_u32(unsigned v) {
    unsigned red = v;
#define DPP_MAX_STEP(CTRL)                                                     \
    {                                                                          \
        const unsigned tpp = (unsigned)__builtin_amdgcn_update_dpp(            \
            0, (int)red, (CTRL), 0xf, 0xf, true);                              \
        red = (tpp > red) ? tpp : red;                                         \
    }
    DPP_MAX_STEP(0x111)   // row_shr:1
    DPP_MAX_STEP(0x112)   // row_shr:2
    DPP_MAX_STEP(0x114)   // row_shr:4
    DPP_MAX_STEP(0x118)   // row_shr:8
    DPP_MAX_STEP(0x142)   // row_bcast:15
    DPP_MAX_STEP(0x143)   // row_bcast:31
#undef DPP_MAX_STEP
    return (unsigned)__builtin_amdgcn_readlane((int)red, 63);
}

// ---------------------------------------------------------------------------
// FPS kernel, one block per batch.
// CORRECTNESS INVARIANTS (proven r0-r21; do not change):
//   * d  = fma(dz,dz, fma(dx,dx, dy*dy))   [XLA contraction form]
//   * md = fminf(D[k], d)
//   * argmax: max value, ties -> LOWEST ORIGINAL point index
//   * emission: idx[t] = last BEFORE the update pass
// HARD RULE (r17/r19): register state arrays touched ONLY by simple unrolled
// loops with static indices.
// r22 machinery (r21 + per-HALF pruning):
//   * each wave's 1024-pt chunk split into two 512-pt halves (k 0..7 / 8..15,
//     contiguous in sorted order) with independent bboxes (in SGPRs via
//     readfirstlane) and independent skip tests vs per-half cached wave max
//     (wbA/wbB). Smaller regions -> higher skip rate + smooths the per-SIMD
//     active-wave straggler term that dominates the iteration.
//   * per-lane cached bvA/bvB (thread best per half) persist across skips;
//     mybits = max(bvA,bvB), bu = max(wbA,wbB) -- no extra DPP for bu.
//   * value-only half-loops (9 ops/pt); gg via r18-proven candidate-only
//     rescan (static D[k] reads, exec-masked, ~1 lane/wave); myPack cached
//     across full skips (r16-proven republish).
//   * tail r21-verbatim: atomicMax u64 rotating cell, ONE barrier, decode,
//     uniform L2 coord fetch, LDS idx ring.
// ---------------------------------------------------------------------------
template <bool FUSED>
__global__ __launch_bounds__(NTH) void fps_kernel(const float* __restrict__ xyz,
                                                  const float* __restrict__ x,
                                                  int* __restrict__ idx_out,
                                                  float* __restrict__ out,
                                                  int S) {
    const int b    = blockIdx.x;
    const int tid  = threadIdx.x;
    const int wid  = tid >> 6;
    const int lane = tid & 63;
    const float* __restrict__ xb = xyz + (size_t)b * 3 * NPTS;

    // 128KB pool: s_ord (64KB) during setup, s_xy (128KB) after.
    __shared__ __align__(16) char s_pool[NPTS * sizeof(f32x2)];
    unsigned* s_ord = (unsigned*)s_pool;
    f32x2*    s_xy  = (f32x2*)s_pool;
    __shared__ unsigned s_hist[256];
    __shared__ unsigned long long s_slot[4];
    __shared__ int s_idx[SMAX];

    // ---- phase 0a: bucket histogram
    for (int i = tid; i < 256; i += NTH) s_hist[i] = 0;
    __syncthreads();
    for (int k = 0; k < PPT; ++k) {
        const int p = k * NTH + tid;
        const unsigned m = morton30(xb[p], xb[NPTS + p], xb[2 * NPTS + p]);
        atomicAdd(&s_hist[m >> 22], 1u);
    }
    __syncthreads();
    // ---- phase 0b: exclusive prefix (serial, one-time)
    if (tid == 0) {
        unsigned acc = 0;
        for (int i = 0; i < 256; ++i) { const unsigned c = s_hist[i]; s_hist[i] = acc; acc += c; }
    }
    __syncthreads();
    // ---- phase 0c: scatter orig indices to sorted order
    for (int k = 0; k < PPT; ++k) {
        const int p = k * NTH + tid;
        const unsigned m = morton30(xb[p], xb[NPTS + p], xb[2 * NPTS + p]);
        const unsigned pos = atomicAdd(&s_hist[m >> 22], 1u);
        s_ord[pos] = (unsigned)p;
    }
    if (tid == 0) { s_slot[0] = s_slot[1] = s_slot[2] = s_slot[3] = 0ull; }
    __syncthreads();

    // ---- phase 0d-1: capture owned orig indices (VI) + Z + D init
    float Z[PPT], D[PPT];
    unsigned VI[PPT / 2];
#pragma unroll
    for (int k = 0; k < PPT; ++k) {
        const unsigned gi = s_ord[wid * (64 * PPT) + k * 64 + lane];
        if ((k & 1) == 0) VI[k >> 1] = gi;
        else              VI[k >> 1] |= (gi << 16);
        Z[k] = xb[2 * NPTS + gi];
        D[k] = INFINITY;
    }
    __syncthreads();   // ALL s_ord reads complete before s_xy overwrites pool

    // ---- phase 0d-2: populate s_xy (one-time re-read from global)
#pragma unroll
    for (int k = 0; k < PPT; ++k) {
        const int p = wid * (64 * PPT) + k * 64 + lane;
        const unsigned gi = (k & 1) ? (VI[k >> 1] >> 16) : (VI[k >> 1] & 0xFFFFu);
        f32x2 v;
        v.x = xb[gi];
        v.y = xb[NPTS + gi];
        s_xy[p] = v;
    }
    __syncthreads();

    // ---- phase 0d-3: per-HALF wave bboxes (A: k 0..7, B: k 8..15)
    float axl =  INFINITY, ayl =  INFINITY, azl =  INFINITY;
    float axh = -INFINITY, ayh = -INFINITY, azh = -INFINITY;
    float bxl =  INFINITY, byl =  INFINITY, bzl =  INFINITY;
    float bxh = -INFINITY, byh = -INFINITY, bzh = -INFINITY;
#pragma unroll
    for (int k = 0; k < PPT; ++k) {
        const f32x2 xy = s_xy[wid * (64 * PPT) + k * 64 + lane];
        if (k < PPT / 2) {
            axl = fminf(axl, xy.x); axh = fmaxf(axh, xy.x);
            ayl = fminf(ayl, xy.y); ayh = fmaxf(ayh, xy.y);
            azl = fminf(azl, Z[k]); azh = fmaxf(azh, Z[k]);
        } else {
            bxl = fminf(bxl, xy.x); bxh = fmaxf(bxh, xy.x);
            byl = fminf(byl, xy.y); byh = fmaxf(byh, xy.y);
            bzl = fminf(bzl, Z[k]); bzh = fmaxf(bzh, Z[k]);
        }
    }
#pragma unroll
    for (int off = 32; off >= 1; off >>= 1) {
        axl = fminf(axl, __shfl_xor(axl, off)); axh = fmaxf(axh, __shfl_xor(axh, off));
        ayl = fminf(ayl, __shfl_xor(ayl, off)); ayh = fmaxf(ayh, __shfl_xor(ayh, off));
        azl = fminf(azl, __shfl_xor(azl, off)); azh = fmaxf(azh, __shfl_xor(azh, off));
        bxl = fminf(bxl, __shfl_xor(bxl, off)); bxh = fmaxf(bxh, __shfl_xor(bxh, off));
        byl = fminf(byl, __shfl_xor(byl, off)); byh = fmaxf(byh, __shfl_xor(byh, off));
        bzl = fminf(bzl, __shfl_xor(bzl, off)); bzh = fmaxf(bzh, __shfl_xor(bzh, off));
    }
    // wave-uniform -> SGPRs (no VGPR pressure, no AGPR parking)
    axl = rfl_f(axl); axh = rfl_f(axh); ayl = rfl_f(ayl); ayh = rfl_f(ayh);
    azl = rfl_f(azl); azh = rfl_f(azh);
    bxl = rfl_f(bxl); bxh = rfl_f(bxh); byl = rfl_f(byl); byh = rfl_f(byh);
    bzl = rfl_f(bzl); bzh = rfl_f(bzh);

    int   last = 0;
    float px = xb[0], py = xb[NPTS], pz = xb[2 * NPTS];
    float bvA = -INFINITY, bvB = -INFINITY;   // per-lane best per half (cached)
    float wbA = INFINITY,  wbB = INFINITY;    // wave max per half (cached)
    unsigned long long myPack = 0;            // cached candidate pack
    const int pbase = wid * (64 * PPT) + lane;

    for (int t = 0; t < S; ++t) {
        if (tid == 0) s_idx[t] = last;        // LDS only - no global store

        // ---- per-half prune tests (uniform; bbox in SGPRs)
        const float gxa = fmaxf(fmaxf(axl - px, px - axh), 0.0f);
        const float gya = fmaxf(fmaxf(ayl - py, py - ayh), 0.0f);
        const float gza = fmaxf(fmaxf(azl - pz, pz - azh), 0.0f);
        const float lbA = gxa * gxa + gya * gya + gza * gza;
        const float gxb = fmaxf(fmaxf(bxl - px, px - bxh), 0.0f);
        const float gyb = fmaxf(fmaxf(byl - py, py - byh), 0.0f);
        const float gzb = fmaxf(fmaxf(bzl - pz, pz - bzh), 0.0f);
        const float lbB = gxb * gxb + gyb * gyb + gzb * gzb;
        const bool actA = !(lbA * PRUNE_C >= wbA);
        const bool actB = !(lbB * PRUNE_C >= wbB);

        if (actA) {
            float bv = -INFINITY;
#pragma unroll
            for (int k = 0; k < PPT / 2; ++k) {
                const f32x2 xy = s_xy[pbase + k * 64];
                const float dx = xy.x - px, dy = xy.y - py, dz = Z[k] - pz;
                const float d  = __builtin_fmaf(dz, dz, __builtin_fmaf(dx, dx, dy * dy));
                const float md = fminf(D[k], d);
                D[k] = md;
                bv = fmaxf(bv, md);
            }
            bvA = bv;
            wbA = __uint_as_float(wave_max_u32(__float_as_uint(bv)));
        }
        if (actB) {
            float bv = -INFINITY;
#pragma unroll
            for (int k = PPT / 2; k < PPT; ++k) {
                const f32x2 xy = s_xy[pbase + k * 64];
                const float dx = xy.x - px, dy = xy.y - py, dz = Z[k] - pz;
                const float d  = __builtin_fmaf(dz, dz, __builtin_fmaf(dx, dx, dy * dy));
                const float md = fminf(D[k], d);
                D[k] = md;
                bv = fmaxf(bv, md);
            }
            bvB = bv;
            wbB = __uint_as_float(wave_max_u32(__float_as_uint(bv)));
        }

        if (actA || actB) {
            const unsigned mybits = __float_as_uint(fmaxf(bvA, bvB));
            const unsigned buA = __float_as_uint(wbA);
            const unsigned buB = __float_as_uint(wbB);
            const unsigned bu  = (buA > buB) ? buA : buB;
            myPack = 0;
            if (mybits == bu) {               // candidate lane(s), ~1 per wave
                unsigned mo = 0xFFFFFFFFu;    // lowest ORIGINAL idx at max
#pragma unroll
                for (int k = 0; k < PPT; ++k) {
                    if (__float_as_uint(D[k]) == mybits) {
                        const unsigned gg = (VI[k >> 1] >> ((k & 1) * 16)) & 0xFFFFu;
                        mo = (gg < mo) ? gg : mo;
                    }
                }
                myPack = ((unsigned long long)mybits << 32)
                       | (unsigned long long)(0xFFFFFFFFu - mo);
            }
        }
        // candidates (fresh or cached from fully-skipped iterations) publish
        if (myPack) atomicMax(&s_slot[t & 3], myPack);
        if (tid == 0) s_slot[(t + 2) & 3] = 0ull;      // distance-2 rotate-init
        __syncthreads();                                // the ONE barrier

        const unsigned long long win = s_slot[t & 3];
        last = (int)(0xFFFFFFFFu - (unsigned)(win & 0xFFFFFFFFull));
        px = xb[last]; py = xb[NPTS + last]; pz = xb[2 * NPTS + last];
    }

    __syncthreads();
    if (!FUSED) {
        for (int i = tid; i < S; i += NTH) idx_out[b * S + i] = s_idx[i];
    } else {
        for (int i = tid; i < CFEAT * S; i += NTH) {
            const int c = i / S, s = i - c * S;
            const long r = (long)b * CFEAT + c;
            out[r * S + s] = x[r * NPTS + s_idx[s]];
        }
        const long base2 = (long)BATCH * CFEAT * S;
        for (int i = tid; i < 3 * S; i += NTH) {
            const int c = i / S, s = i - c * S;
            const long r = (long)b * 3 + c;
            out[base2 + r * S + s] = xyz[r * NPTS + s_idx[s]];
        }
    }
}

// ---------------------------------------------------------------------------
// Gather kernel (full-chip): out = concat( x_s [B][C][S], xyz_s [B][3][S] ).
// ---------------------------------------------------------------------------
__global__ void gather_kernel(const float* __restrict__ x,
                              const float* __restrict__ xyz,
                              const int* __restrict__ idx,
                              float* __restrict__ out,
                              int S) {
    const long nxs   = (long)BATCH * CFEAT * S;
    const long total = nxs + (long)BATCH * 3 * S;
    for (long i = (long)blockIdx.x * blockDim.x + threadIdx.x; i < total;
         i += (long)gridDim.x * blockDim.x) {
        if (i < nxs) {
            const int s  = (int)(i % S);
            const long r = i / S;            // b*C + c
            const int b  = (int)(r / CFEAT);
            const int p  = idx[b * S + s];
            out[i] = x[r * NPTS + p];
        } else {
            const long j = i - nxs;
            const int s  = (int)(j % S);
            const long r = j / S;            // b*3 + c
            const int b  = (int)(r / 3);
            const int p  = idx[b * S + s];
            out[i] = xyz[r * NPTS + p];
        }
    }
}

extern "C" void kernel_launch(void* const* d_in, const int* in_sizes, int n_in,
                              void* d_out, int out_size, void* d_ws, size_t ws_size,
                              hipStream_t stream) {
    const float* x   = nullptr;   // [B, C, N]
    const float* xyz = nullptr;   // [B, 3, N]
    for (int i = 0; i < n_in; ++i) {
        if (in_sizes[i] == BATCH * CFEAT * NPTS)  x   = (const float*)d_in[i];
        else if (in_sizes[i] == BATCH * 3 * NPTS) xyz = (const float*)d_in[i];
    }
    float* out = (float*)d_out;
    const int S = out_size / (BATCH * (CFEAT + 3));

    const size_t need = (size_t)BATCH * (size_t)S * sizeof(int);
    if (ws_size >= need && d_ws != nullptr) {
        int* idx = (int*)d_ws;
        fps_kernel<false><<<BATCH, NTH, 0, stream>>>(xyz, nullptr, idx, nullptr, S);
        gather_kernel<<<2048, 256, 0, stream>>>(x, xyz, idx, out, S);
    } else {
        fps_kernel<true><<<BATCH, NTH, 0, stream>>>(xyz, x, nullptr, out, S);
    }
}

// Round 23
// 4139.817 us; speedup vs baseline: 1.1248x; 1.1248x over previous
//
#include <hip/hip_runtime.h>
#include <hip/hip_bf16.h>

#pragma clang fp contract(off)

#define NTH   1024      // 16 waves, 1 block per CU
#define PPT   16        // NTH*PPT == NPTS
#define NPTS  16384
#define BATCH 16
#define CFEAT 128
#define SMAX  4096
#define NWAVE (NTH / 64)
// Prune margin (r15-proven exact): skip iff lb*PRUNE_C >= waveMaxD.
#define PRUNE_C 0.999995f

typedef __attribute__((ext_vector_type(2))) float f32x2;

__device__ __forceinline__ unsigned spread3(unsigned v) {
    v &= 0x3FFu;
    v = (v | (v << 16)) & 0x030000FFu;
    v = (v | (v << 8))  & 0x0300F00Fu;
    v = (v | (v << 4))  & 0x030C30C3u;
    v = (v | (v << 2))  & 0x09249249u;
    return v;
}
__device__ __forceinline__ unsigned qz10(float v) {
    int q = (int)((v + 6.0f) * (1023.0f / 12.0f));   // layout-only
    q = q < 0 ? 0 : (q > 1023 ? 1023 : q);
    return (unsigned)q;
}
__device__ __forceinline__ unsigned morton30(float x, float y, float z) {
    return (spread3(qz10(x)) << 2) | (spread3(qz10(y)) << 1) | spread3(qz10(z));
}

// ---------------------------------------------------------------------------
// FPS kernel, one block per batch.  FINAL (r21 structure, session best).
// CORRECTNESS INVARIANTS (proven r0-r22; do not change):
//   * d  = fma(dz,dz, fma(dx,dx, dy*dy))   [XLA contraction form]
//   * md = fminf(D[k], d)
//   * argmax: max value, ties -> LOWEST ORIGINAL point index
//   * emission: idx[t] = last BEFORE the update pass
// HARD RULE (r17/r19 regressions): register state arrays are touched ONLY by
// the simple unrolled update loop (static indices, no select-chained reads).
// Structure (each piece isolated-proven):
//   * counting sort on 256 morton buckets (r17): layout-only, conflict-light.
//   * XY in LDS (128KB pool aliasing the sort's dead s_ord), Z/D/VI in regs:
//     demand ~= the ~52 arch VGPRs the allocator grants => no AGPR parking
//     of hot state (r21, the biggest single win after r8).
//   * wave bbox pruning, skip iff lb*PRUNE_C >= cached waveMax(D) (r15 exact-
//     ness proof: skipped updates are bitwise no-ops). Per-wave granularity
//     is the optimum (r22's per-half version regressed).
//   * value-only update (8-9 VALU/pt) + online (bestv,bgg) tracking (r20).
//   * DPP u32 wave max (r13 ctrl sequence) + pack atomicMax into a rotating
//     4-slot LDS u64 cell (r16: integer max == frozen total order; distance-2
//     rotate-init race-free) -> ONE barrier per iteration (r18).
//   * idx ring in LDS, dumped post-loop (r18: removes in-loop global store).
//   * uniform L2 coord fetch for the new pick.
// Perf: 4.04 ms measured (44.4 ms naive-correct baseline, 11x). Latency-bound
// by 4096 dependent iterations on 16/256 CUs (HBM 0.006%, VALU 4.3%) — an
// algorithmic serialization floor, not a HW roofline.
// ---------------------------------------------------------------------------
template <bool FUSED>
__global__ __launch_bounds__(NTH) void fps_kernel(const float* __restrict__ xyz,
                                                  const float* __restrict__ x,
                                                  int* __restrict__ idx_out,
                                                  float* __restrict__ out,
                                                  int S) {
    const int b    = blockIdx.x;
    const int tid  = threadIdx.x;
    const int wid  = tid >> 6;
    const int lane = tid & 63;
    const float* __restrict__ xb = xyz + (size_t)b * 3 * NPTS;

    // 128KB pool: s_ord (64KB) lives here during setup, s_xy (128KB) after.
    __shared__ __align__(16) char s_pool[NPTS * sizeof(f32x2)];
    unsigned* s_ord = (unsigned*)s_pool;
    f32x2*    s_xy  = (f32x2*)s_pool;
    __shared__ unsigned s_hist[256];
    __shared__ unsigned long long s_slot[4];
    __shared__ int s_idx[SMAX];

    // ---- phase 0a: bucket histogram
    for (int i = tid; i < 256; i += NTH) s_hist[i] = 0;
    __syncthreads();
    for (int k = 0; k < PPT; ++k) {
        const int p = k * NTH + tid;
        const unsigned m = morton30(xb[p], xb[NPTS + p], xb[2 * NPTS + p]);
        atomicAdd(&s_hist[m >> 22], 1u);
    }
    __syncthreads();
    // ---- phase 0b: exclusive prefix (serial, one-time)
    if (tid == 0) {
        unsigned acc = 0;
        for (int i = 0; i < 256; ++i) { const unsigned c = s_hist[i]; s_hist[i] = acc; acc += c; }
    }
    __syncthreads();
    // ---- phase 0c: scatter orig indices to sorted order
    for (int k = 0; k < PPT; ++k) {
        const int p = k * NTH + tid;
        const unsigned m = morton30(xb[p], xb[NPTS + p], xb[2 * NPTS + p]);
        const unsigned pos = atomicAdd(&s_hist[m >> 22], 1u);
        s_ord[pos] = (unsigned)p;
    }
    if (tid == 0) { s_slot[0] = s_slot[1] = s_slot[2] = s_slot[3] = 0ull; }
    __syncthreads();

    // ---- phase 0d-1: capture owned orig indices (VI) + Z + D init
    float Z[PPT], D[PPT];
    unsigned VI[PPT / 2];
#pragma unroll
    for (int k = 0; k < PPT; ++k) {
        const unsigned gi = s_ord[wid * (64 * PPT) + k * 64 + lane];
        if ((k & 1) == 0) VI[k >> 1] = gi;
        else              VI[k >> 1] |= (gi << 16);
        Z[k] = xb[2 * NPTS + gi];
        D[k] = INFINITY;
    }
    __syncthreads();   // ALL s_ord reads complete before s_xy overwrites pool

    // ---- phase 0d-2: populate s_xy (re-read coords from global; one-time)
#pragma unroll
    for (int k = 0; k < PPT; ++k) {
        const int p = wid * (64 * PPT) + k * 64 + lane;
        const unsigned gi = (k & 1) ? (VI[k >> 1] >> 16) : (VI[k >> 1] & 0xFFFFu);
        f32x2 v;
        v.x = xb[gi];
        v.y = xb[NPTS + gi];
        s_xy[p] = v;
    }
    __syncthreads();

    // ---- phase 0d-3: wave bbox (xy from LDS, z from regs)
    float bxl =  INFINITY, byl =  INFINITY, bzl =  INFINITY;
    float bxh = -INFINITY, byh = -INFINITY, bzh = -INFINITY;
#pragma unroll
    for (int k = 0; k < PPT; ++k) {
        const f32x2 xy = s_xy[wid * (64 * PPT) + k * 64 + lane];
        bxl = fminf(bxl, xy.x); bxh = fmaxf(bxh, xy.x);
        byl = fminf(byl, xy.y); byh = fmaxf(byh, xy.y);
        bzl = fminf(bzl, Z[k]); bzh = fmaxf(bzh, Z[k]);
    }
#pragma unroll
    for (int off = 32; off >= 1; off >>= 1) {
        bxl = fminf(bxl, __shfl_xor(bxl, off)); bxh = fmaxf(bxh, __shfl_xor(bxh, off));
        byl = fminf(byl, __shfl_xor(byl, off)); byh = fmaxf(byh, __shfl_xor(byh, off));
        bzl = fminf(bzl, __shfl_xor(bzl, off)); bzh = fmaxf(bzh, __shfl_xor(bzh, off));
    }

    int   last  = 0;
    float px = xb[0], py = xb[NPTS], pz = xb[2 * NPTS];
    float wBest = INFINITY;           // cached wave max (valid across skips)
    unsigned long long myPack = 0;    // cached candidate pack (per lane)
    const int pbase = wid * (64 * PPT) + lane;

    for (int t = 0; t < S; ++t) {
        if (tid == 0) s_idx[t] = last;          // LDS only - no global store

        // ---- wave-level prune test (uniform operands)
        const float gx = fmaxf(fmaxf(bxl - px, px - bxh), 0.0f);
        const float gy = fmaxf(fmaxf(byl - py, py - byh), 0.0f);
        const float gz = fmaxf(fmaxf(bzl - pz, pz - bzh), 0.0f);
        const float lb = gx * gx + gy * gy + gz * gz;

        if (!(lb * PRUNE_C >= wBest)) {
            // ---- update: xy from LDS, Z/D/VI in arch regs; online (bestv,bgg)
            float    bestv = -INFINITY;
            unsigned bgg   = 0xFFFFu;
#pragma unroll
            for (int k = 0; k < PPT; ++k) {
                const f32x2 xy = s_xy[pbase + k * 64];
                const float dx = xy.x - px, dy = xy.y - py, dz = Z[k] - pz;
                const float d  = __builtin_fmaf(dz, dz, __builtin_fmaf(dx, dx, dy * dy));
                const float md = fminf(D[k], d);
                D[k] = md;
                const unsigned gg = (k & 1) ? (VI[k >> 1] >> 16)
                                            : (VI[k >> 1] & 0xFFFFu);
                if (md > bestv) { bestv = md; bgg = gg; }   // lowest k at max
            }
            const unsigned mybits = __float_as_uint(bestv);

            // ---- wave max via DPP (r13-proven ctrl sequence)
            unsigned red = mybits;
#define DPP_MAX_STEP(CTRL)                                                     \
            {                                                                  \
                const unsigned tpp = (unsigned)__builtin_amdgcn_update_dpp(    \
                    0, (int)red, (CTRL), 0xf, 0xf, true);                      \
                red = (tpp > red) ? tpp : red;                                 \
            }
            DPP_MAX_STEP(0x111)   // row_shr:1
            DPP_MAX_STEP(0x112)   // row_shr:2
            DPP_MAX_STEP(0x114)   // row_shr:4
            DPP_MAX_STEP(0x118)   // row_shr:8
            DPP_MAX_STEP(0x142)   // row_bcast:15
            DPP_MAX_STEP(0x143)   // row_bcast:31
#undef DPP_MAX_STEP
            const unsigned bu = (unsigned)__builtin_amdgcn_readlane((int)red, 63);
            wBest = __uint_as_float(bu);

            myPack = 0;
            if (mybits == bu) {               // candidate lane(s), ~1 per wave
                myPack = ((unsigned long long)mybits << 32)
                       | (unsigned long long)(0xFFFFFFFFu - bgg);
            }
        }
        // candidates (fresh or cached from skipped iterations) publish
        if (myPack) atomicMax(&s_slot[t & 3], myPack);
        if (tid == 0) s_slot[(t + 2) & 3] = 0ull;      // distance-2 rotate-init
        __syncthreads();                                // the ONE barrier

        const unsigned long long win = s_slot[t & 3];
        last = (int)(0xFFFFFFFFu - (unsigned)(win & 0xFFFFFFFFull));
        px = xb[last]; py = xb[NPTS + last]; pz = xb[2 * NPTS + last];
    }

    __syncthreads();
    if (!FUSED) {
        for (int i = tid; i < S; i += NTH) idx_out[b * S + i] = s_idx[i];
    } else {
        for (int i = tid; i < CFEAT * S; i += NTH) {
            const int c = i / S, s = i - c * S;
            const long r = (long)b * CFEAT + c;
            out[r * S + s] = x[r * NPTS + s_idx[s]];
        }
        const long base2 = (long)BATCH * CFEAT * S;
        for (int i = tid; i < 3 * S; i += NTH) {
            const int c = i / S, s = i - c * S;
            const long r = (long)b * 3 + c;
            out[base2 + r * S + s] = xyz[r * NPTS + s_idx[s]];
        }
    }
}

// ---------------------------------------------------------------------------
// Gather kernel (full-chip): out = concat( x_s [B][C][S], xyz_s [B][3][S] ).
// ---------------------------------------------------------------------------
__global__ void gather_kernel(const float* __restrict__ x,
                              const float* __restrict__ xyz,
                              const int* __restrict__ idx,
                              float* __restrict__ out,
                              int S) {
    const long nxs   = (long)BATCH * CFEAT * S;
    const long total = nxs + (long)BATCH * 3 * S;
    for (long i = (long)blockIdx.x * blockDim.x + threadIdx.x; i < total;
         i += (long)gridDim.x * blockDim.x) {
        if (i < nxs) {
            const int s  = (int)(i % S);
            const long r = i / S;            // b*C + c
            const int b  = (int)(r / CFEAT);
            const int p  = idx[b * S + s];
            out[i] = x[r * NPTS + p];
        } else {
            const long j = i - nxs;
            const int s  = (int)(j % S);
            const long r = j / S;            // b*3 + c
            const int b  = (int)(r / 3);
            const int p  = idx[b * S + s];
            out[i] = xyz[r * NPTS + p];
        }
    }
}

extern "C" void kernel_launch(void* const* d_in, const int* in_sizes, int n_in,
                              void* d_out, int out_size, void* d_ws, size_t ws_size,
                              hipStream_t stream) {
    const float* x   = nullptr;   // [B, C, N]
    const float* xyz = nullptr;   // [B, 3, N]
    for (int i = 0; i < n_in; ++i) {
        if (in_sizes[i] == BATCH * CFEAT * NPTS)  x   = (const float*)d_in[i];
        else if (in_sizes[i] == BATCH * 3 * NPTS) xyz = (const float*)d_in[i];
    }
    float* out = (float*)d_out;
    const int S = out_size / (BATCH * (CFEAT + 3));

    const size_t need = (size_t)BATCH * (size_t)S * sizeof(int);
    if (ws_size >= need && d_ws != nullptr) {
        int* idx = (int*)d_ws;
        fps_kernel<false><<<BATCH, NTH, 0, stream>>>(xyz, nullptr, idx, nullptr, S);
        gather_kernel<<<2048, 256, 0, stream>>>(x, xyz, idx, out, S);
    } else {
        fps_kernel<true><<<BATCH, NTH, 0, stream>>>(xyz, x, nullptr, out, S);
    }
}